// Round 9
// baseline (30.752 us; speedup 1.0000x reference)
//
#include <hip/hip_runtime.h>

#define NN 1024
#define DD 256
#define HH 256

typedef __attribute__((ext_vector_type(8))) short short8;
typedef __attribute__((ext_vector_type(4))) float floatx4;
typedef __attribute__((ext_vector_type(4))) unsigned int uint4v;
typedef _Float16 half2v __attribute__((ext_vector_type(2)));

// ---- ws layout (bytes) ----
// Permuted h' space: 288 slots = [positives (P) | zero-pad to P32 | negatives | zero-pad]
// 144 h-pairs (hp), 36 hp-groups (hpg = hp/4); every hpg (8 h') is sign-uniform
// because P32 is a multiple of 32 and pad rows are all-zero (sign-agnostic).
#define ZB_OFF   0u           // bf16 zb[1024][256]                      512 KiB
#define WC_OFF   524288u      // bf16 Wcat[592][256] (R-half |w2|, C-half -|w2|, wc, pad)
#define B1F_OFF  827392u      // f32 b1f[592]
#define PV_OFF   829760u      // int P (count of w2>0)
#define R2_OFF   1048576u     // u32 R2[144][1024]: pk-f16 pair (2hp,2hp+1) of R~ for row i
#define CT_OFF   1703936u     // u32 Ct[36][1024][4]: pk-f16 C~ pairs, [hpg][j][hp&3]
#define KV_OFF   2293760u     // f32 Kv[1024]  (= z@wc + b2)

__device__ __forceinline__ unsigned short f2bf(float x) {  // RNE f32->bf16
  unsigned u = __float_as_uint(x);
  return (unsigned short)((u + 0x7FFFu + ((u >> 16) & 1u)) >> 16);
}

__device__ __forceinline__ unsigned int pkf16(float a, float b) {
  unsigned int lo = (unsigned int)__builtin_bit_cast(unsigned short, (_Float16)a);
  unsigned int hi = (unsigned int)__builtin_bit_cast(unsigned short, (_Float16)b);
  return lo | (hi << 16);
}

// core: acc += dot2( pk_max(r, c), mul )   -- 2 instr per 2 h per output
__device__ __forceinline__ void pkmaxdot(unsigned int r, unsigned int c,
                                         unsigned int mul, float& acc) {
  unsigned int m;
  asm("v_pk_max_f16 %0, %1, %2" : "=v"(m) : "v"(r), "v"(c));
#if __has_builtin(__builtin_amdgcn_fdot2)
  acc = __builtin_amdgcn_fdot2(__builtin_bit_cast(half2v, m),
                               __builtin_bit_cast(half2v, mul), acc, false);
#else
  asm("v_dot2_f32_f16 %0, %1, %2, %0" : "+v"(acc) : "v"(m), "v"(mul));
#endif
}

// ---------------- k0: prep (unchanged, proven r2-r8) ----------------
__global__ __launch_bounds__(256) void k0_prep(const float* __restrict__ z,
    const float* __restrict__ W1, const float* __restrict__ b1,
    const float* __restrict__ W2, const float* __restrict__ b2,
    char* __restrict__ ws) {
  const int b = blockIdx.x, t = threadIdx.x;
  unsigned short* zb = (unsigned short*)(ws + ZB_OFF);
  unsigned short* Wc = (unsigned short*)(ws + WC_OFF);
  float* b1f = (float*)(ws + B1F_OFF);

  if (b < 256) {
    const int g = b * 256 + t;
    float4 v = ((const float4*)z)[g];
    ushort4 u;
    u.x = f2bf(v.x); u.y = f2bf(v.y); u.z = f2bf(v.z); u.w = f2bf(v.w);
    ((ushort4*)zb)[g] = u;
    return;
  }
  if (b < 400) {
    __shared__ unsigned long long masks[4];
    __shared__ short inv[288];
    const bool pos = W2[t] > 0.f;
    unsigned long long m = __ballot(pos);
    if ((t & 63) == 0) masks[t >> 6] = m;
    inv[t] = -1;
    if (t < 32) inv[256 + t] = -1;
    __syncthreads();
    int P = 0;
    #pragma unroll
    for (int w = 0; w < 4; ++w) P += __popcll(masks[w]);
    const int w = t >> 6;
    int below = __popcll(masks[w] & ((1ull << (t & 63)) - 1ull));
    #pragma unroll
    for (int wi = 0; wi < 4; ++wi) if (wi < w) below += __popcll(masks[wi]);
    const int P32 = (P + 31) & ~31;
    const int dest = pos ? below : (P32 + (t - below));
    inv[dest] = (short)t;
    __syncthreads();

    const int q = (b - 256) * 4 + (t >> 6);     // 0..575
    const int d0 = (t & 63) * 4;
    const bool topR = q < 288;
    const int hidx = topR ? q : q - 288;
    const short oh = inv[hidx];
    ushort4 u = {0, 0, 0, 0};
    float bias = 0.f;
    if (oh >= 0) {
      const float wa = fabsf(W2[oh]);
      const float sc = topR ? wa : -wa;
      const float4 v = *(const float4*)(W1 + oh * 512 + (topR ? 0 : 256) + d0);
      u.x = f2bf(v.x * sc); u.y = f2bf(v.y * sc);
      u.z = f2bf(v.z * sc); u.w = f2bf(v.w * sc);
      bias = topR ? b1[oh] * wa : 0.f;
    }
    ((ushort4*)(Wc + q * 256))[d0 >> 2] = u;
    if (d0 == 0) b1f[q] = bias;
    if (b == 256 && t == 0) *(int*)(ws + PV_OFF) = P;
    return;
  }
  {
    __shared__ float part[4][64];
    const int w = t >> 6, dl = t & 63;
    const int d = (b - 400) * 64 + dl;
    float acc = 0.f;
    const float* col = W1 + 256 + d;
    #pragma unroll 8
    for (int h = w * 64; h < w * 64 + 64; ++h) acc += W2[h] * col[h * 512];
    part[w][dl] = acc;
    __syncthreads();
    if (w == 0) {
      float s = part[0][dl] + part[1][dl] + part[2][dl] + part[3][dl];
      Wc[576 * 256 + d] = f2bf(s);
    }
    if (b == 400) {
      for (int r = 577; r < 592; ++r) Wc[r * 256 + t] = 0;
      if (t == 0) b1f[576] = b2[0];
      if (t < 15) b1f[577 + t] = 0.f;
    }
  }
}

// ---------------- k1: fc1 GEMM via bf16 MFMA -> pk-f16 (batched: 4 q-tiles/block) ----------------
// 256-thr block, wave w handles q-tile (by*4+w); grid (64,10) = 640 blocks (was 2368 1-wave).
__global__ __launch_bounds__(256) void k1_mfma(char* __restrict__ ws) {
  __shared__ float tile[4][16][17];
  const unsigned short* zb = (const unsigned short*)(ws + ZB_OFF);
  const unsigned short* Wcu = (const unsigned short*)(ws + WC_OFF);
  const float* b1f = (const float*)(ws + B1F_OFF);
  unsigned int* R2 = (unsigned int*)(ws + R2_OFF);
  unsigned int* Ct = (unsigned int*)(ws + CT_OFF);
  float* Kv = (float*)(ws + KV_OFF);

  const int t = threadIdx.x;
  const int l = t & 63, w = t >> 6;
  const int i0 = blockIdx.x * 16;
  const int tid = blockIdx.y * 4 + w;          // q-tile id, 0..39
  const bool valid = tid < 37;
  const int q0 = tid * 16;                      // 0..576(+)

  floatx4 acc = {0.f, 0.f, 0.f, 0.f};
  if (valid) {
    const short* A = (const short*)zb + (i0 + (l & 15)) * 256 + ((l >> 4) * 8);
    const short* B = (const short*)Wcu + (q0 + (l & 15)) * 256 + ((l >> 4) * 8);
    #pragma unroll
    for (int kk = 0; kk < 8; ++kk) {
      short8 a  = *(const short8*)(A + kk * 32);
      short8 bb = *(const short8*)(B + kk * 32);
      acc = __builtin_amdgcn_mfma_f32_16x16x32_bf16(a, bb, acc, 0, 0, 0);
    }
  }
  const int col = l & 15, r0 = (l >> 4) * 4;   // D: col=lane&15, row=(lane>>4)*4+reg
  if (valid && q0 < 576) {
    const float bias = b1f[q0 + col];
    #pragma unroll
    for (int q = 0; q < 4; ++q) tile[w][r0 + q][col] = acc[q] + bias;
  }
  __syncthreads();                              // unconditional: all 256 threads
  if (valid) {
    const int il = l & 15, g2 = l >> 4;        // g2 in 0..3
    if (q0 < 288) {
      #pragma unroll
      for (int e = 0; e < 2; ++e) {
        const int qc = g2 * 4 + e * 2;
        const unsigned int pk = pkf16(tile[w][il][qc], tile[w][il][qc + 1]);
        R2[((q0 >> 1) + g2 * 2 + e) * 1024 + (i0 + il)] = pk;
      }
    } else if (q0 < 576) {
      unsigned int pk0 = pkf16(tile[w][il][g2 * 4 + 0], tile[w][il][g2 * 4 + 1]);
      unsigned int pk1 = pkf16(tile[w][il][g2 * 4 + 2], tile[w][il][g2 * 4 + 3]);
      const int hpg = ((q0 - 288) >> 3) + (g2 >> 1);
      unsigned int* dst = Ct + (hpg * 1024 + (i0 + il)) * 4 + (g2 & 1) * 2;
      dst[0] = pk0; dst[1] = pk1;
    } else if (col == 0) {
      const float bias = b1f[576];             // = b2
      #pragma unroll
      for (int q = 0; q < 4; ++q) Kv[i0 + r0 + q] = acc[q] + bias;
    }
  }
}

// ---------------- k2: pairwise decode, balanced 9-hpg/wave, 3-buf depth-2 stream ----------------
// Block 256 thr (4 waves), tile 16i x 64j. Wave w owns hpgs [9w, 9w+9) (all sign-uniform,
// perfectly balanced -- r8's {3,2,2,2} chunk split had a 33% wave-0 tail).
// C prefetched 2 batches ahead through 3 named reg buffers (no chunk-restart stalls).
__global__ __launch_bounds__(256) void k2_pair(const unsigned int* __restrict__ R2,
    const unsigned int* __restrict__ Ct, const float* __restrict__ Kv,
    const int* __restrict__ Pp, float* __restrict__ out) {
  __shared__ unsigned int Rl[144][16];     // 9 KiB
  __shared__ float part[4][16][64];        // 16 KiB
  const int t = threadIdx.x;
  const int lane = t & 63, w = t >> 6;
  const int li = lane >> 4, lj = lane & 15;
  const int i0 = blockIdx.x * 16, j0 = blockIdx.y * 64;

  // stage R: 2304 u32, 9 per thread, 64B-coalesced in 16-lane groups
  #pragma unroll
  for (int k = 0; k < 9; ++k) {
    const int n = k * 256 + t;
    ((unsigned int*)Rl)[n] = R2[(n >> 4) * 1024 + i0 + (n & 15)];
  }
  __syncthreads();

  const int P32 = (Pp[0] + 31) & ~31;
  const int hbase = w * 9;                 // this wave's hpg range
  float acc[4][4] = {};

#define LOADC(BUF, G) do { \
    _Pragma("unroll") \
    for (int jj = 0; jj < 4; ++jj) \
      BUF[jj] = *(const uint4v*)(Ct + (((hbase + (G)) * 1024) + j0 + lj + 16 * jj) * 4); \
  } while (0)

#define COMPG(BUF, G) do { \
    const unsigned int mul = ((hbase + (G)) * 8 < P32) ? 0x3C003C00u : 0xBC00BC00u; \
    _Pragma("unroll") \
    for (int hp2 = 0; hp2 < 4; ++hp2) { \
      const uint4v ra = *(const uint4v*)&Rl[(hbase + (G)) * 4 + hp2][li * 4]; \
      _Pragma("unroll") \
      for (int ii = 0; ii < 4; ++ii) \
        _Pragma("unroll") \
        for (int jj = 0; jj < 4; ++jj) \
          pkmaxdot(ra[ii], BUF[jj][hp2], mul, acc[ii][jj]); \
    } \
  } while (0)

  {
    uint4v A[4], B[4], C[4];
    LOADC(A, 0); LOADC(B, 1); LOADC(C, 2);
    COMPG(A, 0); LOADC(A, 3);
    COMPG(B, 1); LOADC(B, 4);
    COMPG(C, 2); LOADC(C, 5);
    COMPG(A, 3); LOADC(A, 6);
    COMPG(B, 4); LOADC(B, 7);
    COMPG(C, 5); LOADC(C, 8);
    COMPG(A, 6);
    COMPG(B, 7);
    COMPG(C, 8);
  }
#undef LOADC
#undef COMPG

  #pragma unroll
  for (int ii = 0; ii < 4; ++ii)
    #pragma unroll
    for (int jj = 0; jj < 4; ++jj)
      part[w][li * 4 + ii][lj + 16 * jj] = acc[ii][jj];
  __syncthreads();

  // combine + sigmoid: 256 threads x 4 outputs
  const int jl = t & 63, ib = (t >> 6) * 4;
  const float kv = Kv[j0 + jl];
  #pragma unroll
  for (int u = 0; u < 4; ++u) {
    const int il = ib + u;
    const float x = part[0][il][jl] + part[1][il][jl] +
                    part[2][il][jl] + part[3][il][jl] + kv;
    out[(i0 + il) * NN + j0 + jl] = 1.f / (1.f + __expf(-x));
  }
}

extern "C" void kernel_launch(void* const* d_in, const int* in_sizes, int n_in,
                              void* d_out, int out_size, void* d_ws, size_t ws_size,
                              hipStream_t stream) {
  const float* z  = (const float*)d_in[0];
  const float* W1 = (const float*)d_in[1];
  const float* b1 = (const float*)d_in[2];
  const float* W2 = (const float*)d_in[3];
  const float* b2 = (const float*)d_in[4];
  float* out = (float*)d_out;
  char* ws = (char*)d_ws;

  k0_prep<<<404, 256, 0, stream>>>(z, W1, b1, W2, b2, ws);
  k1_mfma<<<dim3(64, 10), 256, 0, stream>>>(ws);
  k2_pair<<<dim3(64, 16), 256, 0, stream>>>(
      (const unsigned int*)(ws + R2_OFF), (const unsigned int*)(ws + CT_OFF),
      (const float*)(ws + KV_OFF), (const int*)(ws + PV_OFF), out);
}

// Round 10
// 28.778 us; speedup vs baseline: 1.0686x; 1.0686x over previous
//
#include <hip/hip_runtime.h>

#define NN 1024

typedef __attribute__((ext_vector_type(8))) short short8;
typedef __attribute__((ext_vector_type(4))) float floatx4;
typedef __attribute__((ext_vector_type(4))) unsigned int uint4v;
typedef _Float16 half2v __attribute__((ext_vector_type(2)));

// ---- ws layout (bytes) ---- (no permutation, no padding: h' = h, 128 hp, 32 hpg)
#define ZB_OFF   0u          // bf16 zb[1024][256]                         512 KiB
#define WC_OFF   524288u     // bf16 Wcat[512][256]: rows 0..255 = |w2_h|*W1[h][0:256]
                             //   rows 256..511 = -|w2_h|*W1[h][256:512]   256 KiB
#define MUL_OFF  786432u     // u32 mulpk[128]: pk-f16 (sgn w2_{2hp}, sgn w2_{2hp+1})
#define R2_OFF   1048576u    // u32 R2[128][1024]: pk-f16 (R~_{2hp}, R~_{2hp+1}) per i
#define CT_OFF   1572864u    // u32 Ct[32][1024][4]: pk-f16 Cn pairs, [hpg][j][hp&3]

__device__ __forceinline__ unsigned short f2bf(float x) {  // RNE f32->bf16
  unsigned u = __float_as_uint(x);
  return (unsigned short)((u + 0x7FFFu + ((u >> 16) & 1u)) >> 16);
}

__device__ __forceinline__ unsigned int pkf16(float a, float b) {
  unsigned int lo = (unsigned int)__builtin_bit_cast(unsigned short, (_Float16)a);
  unsigned int hi = (unsigned int)__builtin_bit_cast(unsigned short, (_Float16)b);
  return lo | (hi << 16);
}

__device__ __forceinline__ void dot2acc(unsigned int a, unsigned int b, float& acc) {
#if __has_builtin(__builtin_amdgcn_fdot2)
  acc = __builtin_amdgcn_fdot2(__builtin_bit_cast(half2v, a),
                               __builtin_bit_cast(half2v, b), acc, false);
#else
  asm("v_dot2_f32_f16 %0, %1, %2, %0" : "+v"(acc) : "v"(a), "v"(b));
#endif
}

// core: acc += dot2( pk_max(r, c), mul )
__device__ __forceinline__ void pkmaxdot(unsigned int r, unsigned int c,
                                         unsigned int mul, float& acc) {
  unsigned int m;
  asm("v_pk_max_f16 %0, %1, %2" : "=v"(m) : "v"(r), "v"(c));
  dot2acc(m, mul, acc);
}

// ---------------- k0: prep (z->bf16; Wcat = +/-|w2|*W1 halves; mul table) ----------------
__global__ __launch_bounds__(256) void k0_prep(const float* __restrict__ z,
    const float* __restrict__ W1, const float* __restrict__ W2,
    char* __restrict__ ws) {
  const int b = blockIdx.x, t = threadIdx.x;
  unsigned short* zb = (unsigned short*)(ws + ZB_OFF);
  unsigned short* Wc = (unsigned short*)(ws + WC_OFF);

  if (b < 256) {                       // z -> bf16, 1 float4 per thread
    const int g = b * 256 + t;
    float4 v = ((const float4*)z)[g];
    ushort4 u;
    u.x = f2bf(v.x); u.y = f2bf(v.y); u.z = f2bf(v.z); u.w = f2bf(v.w);
    ((ushort4*)zb)[g] = u;
    return;
  }
  if (b < 384) {                       // Wcat row q = 4*(b-256)+(t>>6), q in [0,512)
    const int q = (b - 256) * 4 + (t >> 6);
    const int d0 = (t & 63) * 4;
    const bool topR = q < 256;
    const int h = q & 255;
    const float wa = fabsf(W2[h]);
    const float sc = topR ? wa : -wa;  // C-half carries the negation (Cn = -C~)
    const float4 v = *(const float4*)(W1 + h * 512 + (topR ? 0 : 256) + d0);
    ushort4 u;
    u.x = f2bf(v.x * sc); u.y = f2bf(v.y * sc);
    u.z = f2bf(v.z * sc); u.w = f2bf(v.w * sc);
    ((ushort4*)(Wc + q * 256))[d0 >> 2] = u;
    return;
  }
  // b == 384: packed sign table
  if (t < 128) {
    const unsigned int s0 = (W2[2 * t]     > 0.f) ? 0x3C00u : 0xBC00u;
    const unsigned int s1 = (W2[2 * t + 1] > 0.f) ? 0x3C00u : 0xBC00u;
    ((unsigned int*)(ws + MUL_OFF))[t] = s0 | (s1 << 16);
  }
}

// ---------------- k1: fc1 GEMM via bf16 MFMA -> pk-f16 R2 / Ct ----------------
// grid (64, 8), 256 thr; wave w handles q-tile by*4+w (32 tiles exactly, no tail).
__global__ __launch_bounds__(256) void k1_mfma(char* __restrict__ ws,
    const float* __restrict__ b1, const float* __restrict__ W2) {
  __shared__ float tile[4][16][17];
  const unsigned short* zb = (const unsigned short*)(ws + ZB_OFF);
  const unsigned short* Wcu = (const unsigned short*)(ws + WC_OFF);
  unsigned int* R2 = (unsigned int*)(ws + R2_OFF);
  unsigned int* Ct = (unsigned int*)(ws + CT_OFF);

  const int t = threadIdx.x;
  const int l = t & 63, w = t >> 6;
  const int i0 = blockIdx.x * 16;
  const int q0 = (blockIdx.y * 4 + w) * 16;     // 0..496

  const short* A = (const short*)zb + (i0 + (l & 15)) * 256 + ((l >> 4) * 8);
  const short* B = (const short*)Wcu + (q0 + (l & 15)) * 256 + ((l >> 4) * 8);
  floatx4 acc = {0.f, 0.f, 0.f, 0.f};
  #pragma unroll
  for (int kk = 0; kk < 8; ++kk) {
    short8 a  = *(const short8*)(A + kk * 32);
    short8 bb = *(const short8*)(B + kk * 32);
    acc = __builtin_amdgcn_mfma_f32_16x16x32_bf16(a, bb, acc, 0, 0, 0);
  }
  const int col = l & 15, r0 = (l >> 4) * 4;    // D: col=lane&15, row=(lane>>4)*4+reg
  float bias = 0.f;
  if (q0 < 256) {                               // R-half: fold |w2|*b1
    const int h = q0 + col;
    bias = b1[h] * fabsf(W2[h]);
  }
  #pragma unroll
  for (int q = 0; q < 4; ++q) tile[w][r0 + q][col] = acc[q] + bias;
  __syncthreads();
  const int il = l & 15, g2 = l >> 4;           // g2 in 0..3
  if (q0 < 256) {
    #pragma unroll
    for (int e = 0; e < 2; ++e) {
      const int qc = g2 * 4 + e * 2;
      const unsigned int pk = pkf16(tile[w][il][qc], tile[w][il][qc + 1]);
      R2[((q0 >> 1) + g2 * 2 + e) * 1024 + (i0 + il)] = pk;
    }
  } else {
    const unsigned int pk0 = pkf16(tile[w][il][g2 * 4 + 0], tile[w][il][g2 * 4 + 1]);
    const unsigned int pk1 = pkf16(tile[w][il][g2 * 4 + 2], tile[w][il][g2 * 4 + 3]);
    const int hpg = ((q0 - 256) >> 3) + (g2 >> 1);
    unsigned int* dst = Ct + (hpg * 1024 + (i0 + il)) * 4 + (g2 & 1) * 2;
    dst[0] = pk0; dst[1] = pk1;
  }
}

// ---------------- k2: pairwise decode, 32i x 64j tile, Kv folded ----------------
// grid (32,16) = 512 blocks, 256 thr (4 waves). Wave w owns hpgs [8w, 8w+8).
// Lane (li 0..3, lj 0..15): i-rows li*8..li*8+7 (acc+acc2), j-cols lj+16*jj.
// out = sigmoid( sum_h s*max(R~,Cn) - sum_h s*Cn + b2 ), kv folded via dot2(Cn,mul).
__global__ __launch_bounds__(256) void k2_pair(const unsigned int* __restrict__ R2,
    const unsigned int* __restrict__ Ct, const unsigned int* __restrict__ Mul,
    const float* __restrict__ b2v, float* __restrict__ out) {
  __shared__ unsigned int Rl[128][32];     // 16 KiB
  __shared__ float part[4][32][65];        // 33.3 KiB (pad 65 vs bank conflicts)
  __shared__ float partkv[4][64];          // 1 KiB
  const int t = threadIdx.x;
  const int lane = t & 63, w = t >> 6;
  const int li = lane >> 4, lj = lane & 15;
  const int i0 = blockIdx.x * 32, j0 = blockIdx.y * 64;

  // stage R: 4096 u32, 16 per thread, 128B-coalesced per 32-lane group
  #pragma unroll
  for (int k = 0; k < 16; ++k) {
    const int n = k * 256 + t;
    Rl[n >> 5][n & 31] = R2[(n >> 5) * 1024 + i0 + (n & 31)];
  }
  __syncthreads();

  const int hbase = w * 8;                 // this wave's hpg range
  float acc[4][4] = {}, acc2[4][4] = {};
  float kvacc[4] = {};

#define LOADC(BUF, MQ, G) do { \
    _Pragma("unroll") \
    for (int jj = 0; jj < 4; ++jj) \
      BUF[jj] = *(const uint4v*)(Ct + (((hbase + (G)) * 1024) + j0 + lj + 16 * jj) * 4); \
    MQ = *(const uint4v*)(Mul + (hbase + (G)) * 4); \
  } while (0)

#define COMPG(BUF, MQ, G) do { \
    _Pragma("unroll") \
    for (int hp2 = 0; hp2 < 4; ++hp2) { \
      const int hp = (hbase + (G)) * 4 + hp2; \
      const uint4v ra0 = *(const uint4v*)&Rl[hp][li * 8]; \
      const uint4v ra1 = *(const uint4v*)&Rl[hp][li * 8 + 4]; \
      const unsigned int mu = MQ[hp2]; \
      _Pragma("unroll") \
      for (int jj = 0; jj < 4; ++jj) { \
        const unsigned int c = BUF[jj][hp2]; \
        dot2acc(c, mu, kvacc[jj]); \
        _Pragma("unroll") \
        for (int ii = 0; ii < 4; ++ii) pkmaxdot(ra0[ii], c, mu, acc[ii][jj]); \
        _Pragma("unroll") \
        for (int ii = 0; ii < 4; ++ii) pkmaxdot(ra1[ii], c, mu, acc2[ii][jj]); \
      } \
    } \
  } while (0)

  {
    uint4v A[4], B[4], C[4];
    uint4v MA, MB, MC;
    LOADC(A, MA, 0); LOADC(B, MB, 1); LOADC(C, MC, 2);
    COMPG(A, MA, 0); LOADC(A, MA, 3);
    COMPG(B, MB, 1); LOADC(B, MB, 4);
    COMPG(C, MC, 2); LOADC(C, MC, 5);
    COMPG(A, MA, 3); LOADC(A, MA, 6);
    COMPG(B, MB, 4); LOADC(B, MB, 7);
    COMPG(C, MC, 5);
    COMPG(A, MA, 6);
    COMPG(B, MB, 7);
  }
#undef LOADC
#undef COMPG

  #pragma unroll
  for (int ii = 0; ii < 4; ++ii)
    #pragma unroll
    for (int jj = 0; jj < 4; ++jj) {
      part[w][li * 8 + ii][lj + 16 * jj]     = acc[ii][jj];
      part[w][li * 8 + 4 + ii][lj + 16 * jj] = acc2[ii][jj];
    }
  if (li == 0) {
    #pragma unroll
    for (int jj = 0; jj < 4; ++jj) partkv[w][lj + 16 * jj] = kvacc[jj];
  }
  __syncthreads();

  // combine + sigmoid: 256 threads x 8 outputs
  const int jl = t & 63, ib = (t >> 6) * 8;
  const float kvt = partkv[0][jl] + partkv[1][jl] + partkv[2][jl] + partkv[3][jl];
  const float base = b2v[0] - kvt;           // Kv[j] = b2 - sum_h s*Cn
  #pragma unroll
  for (int u = 0; u < 8; ++u) {
    const int il = ib + u;
    const float x = part[0][il][jl] + part[1][il][jl] +
                    part[2][il][jl] + part[3][il][jl] + base;
    out[(i0 + il) * NN + j0 + jl] = 1.f / (1.f + __expf(-x));
  }
}

extern "C" void kernel_launch(void* const* d_in, const int* in_sizes, int n_in,
                              void* d_out, int out_size, void* d_ws, size_t ws_size,
                              hipStream_t stream) {
  const float* z  = (const float*)d_in[0];
  const float* W1 = (const float*)d_in[1];
  const float* b1 = (const float*)d_in[2];
  const float* W2 = (const float*)d_in[3];
  const float* b2 = (const float*)d_in[4];
  float* out = (float*)d_out;
  char* ws = (char*)d_ws;

  k0_prep<<<385, 256, 0, stream>>>(z, W1, W2, ws);
  k1_mfma<<<dim3(64, 8), 256, 0, stream>>>(ws, b1, W2);
  k2_pair<<<dim3(32, 16), 256, 0, stream>>>(
      (const unsigned int*)(ws + R2_OFF), (const unsigned int*)(ws + CT_OFF),
      (const unsigned int*)(ws + MUL_OFF), b2, out);
}

// Round 11
// 22.995 us; speedup vs baseline: 1.3374x; 1.2515x over previous
//
#include <hip/hip_runtime.h>

#define NN 1024

typedef __attribute__((ext_vector_type(8))) short short8;
typedef __attribute__((ext_vector_type(4))) float floatx4;
typedef __attribute__((ext_vector_type(4))) unsigned int uint4v;
typedef _Float16 half2v __attribute__((ext_vector_type(2)));

// ---- ws layout (bytes) ----  (k0 deleted: only the GEMM outputs live in ws)
#define R2_OFF   0u          // u32 R2[128][1024]: pk-f16 (R~_{2hp}, R~_{2hp+1}) per i
#define CT_OFF   524288u     // u32 Ct[32][1024][4]: pk-f16 Cn pairs, [hpg][j][hp&3]

__device__ __forceinline__ unsigned short f2bf(float x) {  // RNE f32->bf16
  unsigned u = __float_as_uint(x);
  return (unsigned short)((u + 0x7FFFu + ((u >> 16) & 1u)) >> 16);
}

__device__ __forceinline__ unsigned int pkf16(float a, float b) {
  unsigned int lo = (unsigned int)__builtin_bit_cast(unsigned short, (_Float16)a);
  unsigned int hi = (unsigned int)__builtin_bit_cast(unsigned short, (_Float16)b);
  return lo | (hi << 16);
}

__device__ __forceinline__ void dot2acc(unsigned int a, unsigned int b, float& acc) {
#if __has_builtin(__builtin_amdgcn_fdot2)
  acc = __builtin_amdgcn_fdot2(__builtin_bit_cast(half2v, a),
                               __builtin_bit_cast(half2v, b), acc, false);
#else
  asm("v_dot2_f32_f16 %0, %1, %2, %0" : "+v"(acc) : "v"(a), "v"(b));
#endif
}

// core: acc += dot2( pk_max(r, c), mul )
__device__ __forceinline__ void pkmaxdot(unsigned int r, unsigned int c,
                                         unsigned int mul, float& acc) {
  unsigned int m;
  asm("v_pk_max_f16 %0, %1, %2" : "=v"(m) : "v"(r), "v"(c));
  dot2acc(m, mul, acc);
}

// ---------------- k1: fused prep + fc1 GEMM (bf16 MFMA) -> pk-f16 R2 / Ct ----------------
// grid (64 ix, 8 qy) x 256 thr. Block stages its z i-tile (shared) and per-wave
// W1 q-slice (scaled +/-|w2|) into LDS as bf16, then MFMA identical to r10's k1.
// LDS rows padded to 272 bf16 (stride = 136 dw = 8 mod 32 -> frag reads ~4-way = cheap).
__global__ __launch_bounds__(256) void k1_fused(const float* __restrict__ z,
    const float* __restrict__ W1, const float* __restrict__ b1,
    const float* __restrict__ W2, char* __restrict__ ws) {
  __shared__ unsigned short zsh[16][272];      // 8.7 KB
  __shared__ unsigned short wsh[4][16][272];   // 34.8 KB
  __shared__ float tile[4][16][17];            // 4.4 KB
  unsigned int* R2 = (unsigned int*)(ws + R2_OFF);
  unsigned int* Ct = (unsigned int*)(ws + CT_OFF);

  const int t = threadIdx.x;
  const int l = t & 63, w = t >> 6;
  const int i0 = blockIdx.x * 16;
  const int tid = blockIdx.y * 4 + w;          // q-tile id 0..31
  const int q0 = tid * 16;                     // 0..496
  const bool topR = q0 < 256;
  const int h0 = q0 & 255;
  const int off = topR ? 0 : 256;

  // stage z i-tile: 1024 float4, 4 per thread, coalesced; convert to bf16
  #pragma unroll
  for (int k = 0; k < 4; ++k) {
    const int f = t + k * 256;                 // float4 index 0..1023
    const int r = f >> 6, c4 = f & 63;
    const float4 v = *(const float4*)(z + (i0 + r) * 256 + c4 * 4);
    ushort4 u;
    u.x = f2bf(v.x); u.y = f2bf(v.y); u.z = f2bf(v.z); u.w = f2bf(v.w);
    *(ushort4*)&zsh[r][c4 * 4] = u;
  }
  // stage W1 q-slice (per wave): row r, lane l reads float4 #l of the 256-f32 row
  #pragma unroll 4
  for (int r = 0; r < 16; ++r) {
    const int h = h0 + r;
    const float wa = fabsf(W2[h]);             // wave-uniform -> scalar
    const float sc = topR ? wa : -wa;          // C-half carries the negation
    const float4 v = *(const float4*)(W1 + h * 512 + off + l * 4);
    ushort4 u;
    u.x = f2bf(v.x * sc); u.y = f2bf(v.y * sc);
    u.z = f2bf(v.z * sc); u.w = f2bf(v.w * sc);
    *(ushort4*)&wsh[w][r][l * 4] = u;
  }
  __syncthreads();

  // MFMA: A = zsh rows (i), B = wsh rows (q); same fragment roles as r10 (verified)
  floatx4 acc = {0.f, 0.f, 0.f, 0.f};
  const int fr = l & 15, fg = (l >> 4) * 8;
  #pragma unroll
  for (int kk = 0; kk < 8; ++kk) {
    const short8 a  = *(const short8*)&zsh[fr][fg + kk * 32];
    const short8 bb = *(const short8*)&wsh[w][fr][fg + kk * 32];
    acc = __builtin_amdgcn_mfma_f32_16x16x32_bf16(a, bb, acc, 0, 0, 0);
  }

  const int col = l & 15, r0 = (l >> 4) * 4;   // D: col=lane&15, row=(lane>>4)*4+reg
  float bias = 0.f;
  if (topR) {                                  // R-half: fold |w2|*b1
    const int h = q0 + col;
    bias = b1[h] * fabsf(W2[h]);
  }
  #pragma unroll
  for (int q = 0; q < 4; ++q) tile[w][r0 + q][col] = acc[q] + bias;
  __syncthreads();
  const int il = l & 15, g2 = l >> 4;          // g2 in 0..3
  if (topR) {
    #pragma unroll
    for (int e = 0; e < 2; ++e) {
      const int qc = g2 * 4 + e * 2;
      const unsigned int pk = pkf16(tile[w][il][qc], tile[w][il][qc + 1]);
      R2[((q0 >> 1) + g2 * 2 + e) * 1024 + (i0 + il)] = pk;
    }
  } else {
    const unsigned int pk0 = pkf16(tile[w][il][g2 * 4 + 0], tile[w][il][g2 * 4 + 1]);
    const unsigned int pk1 = pkf16(tile[w][il][g2 * 4 + 2], tile[w][il][g2 * 4 + 3]);
    const int hpg = ((q0 - 256) >> 3) + (g2 >> 1);
    unsigned int* dst = Ct + (hpg * 1024 + (i0 + il)) * 4 + (g2 & 1) * 2;
    dst[0] = pk0; dst[1] = pk1;
  }
}

// ---------------- k2: pairwise decode (r10 core, unchanged) + in-block sign table ----------------
// grid (32,16) = 512 blocks, 256 thr (4 waves). Wave w owns hpgs [8w, 8w+8).
// out = sigmoid( sum_h s*max(R~,Cn) - sum_h s*Cn + b2 ), kv folded via dot2(Cn,mul).
__global__ __launch_bounds__(256) void k2_pair(const unsigned int* __restrict__ R2,
    const unsigned int* __restrict__ Ct, const float* __restrict__ W2,
    const float* __restrict__ b2v, float* __restrict__ out) {
  __shared__ unsigned int Rl[128][32];     // 16 KiB
  __shared__ float part[4][32][65];        // 33.3 KiB
  __shared__ float partkv[4][64];          // 1 KiB
  __shared__ unsigned int MulS[128];       // 0.5 KiB
  const int t = threadIdx.x;
  const int lane = t & 63, w = t >> 6;
  const int li = lane >> 4, lj = lane & 15;
  const int i0 = blockIdx.x * 32, j0 = blockIdx.y * 64;

  // in-block sign table (replaces k0's global table)
  if (t < 128) {
    const unsigned int s0 = (W2[2 * t]     > 0.f) ? 0x3C00u : 0xBC00u;
    const unsigned int s1 = (W2[2 * t + 1] > 0.f) ? 0x3C00u : 0xBC00u;
    MulS[t] = s0 | (s1 << 16);
  }
  // stage R: 4096 u32, 16 per thread, 128B-coalesced per 32-lane group
  #pragma unroll
  for (int k = 0; k < 16; ++k) {
    const int n = k * 256 + t;
    Rl[n >> 5][n & 31] = R2[(n >> 5) * 1024 + i0 + (n & 31)];
  }
  __syncthreads();

  const int hbase = w * 8;                 // this wave's hpg range
  float acc[4][4] = {}, acc2[4][4] = {};
  float kvacc[4] = {};

#define LOADC(BUF, MQ, G) do { \
    _Pragma("unroll") \
    for (int jj = 0; jj < 4; ++jj) \
      BUF[jj] = *(const uint4v*)(Ct + (((hbase + (G)) * 1024) + j0 + lj + 16 * jj) * 4); \
    MQ = *(const uint4v*)&MulS[(hbase + (G)) * 4]; \
  } while (0)

#define COMPG(BUF, MQ, G) do { \
    _Pragma("unroll") \
    for (int hp2 = 0; hp2 < 4; ++hp2) { \
      const int hp = (hbase + (G)) * 4 + hp2; \
      const uint4v ra0 = *(const uint4v*)&Rl[hp][li * 8]; \
      const uint4v ra1 = *(const uint4v*)&Rl[hp][li * 8 + 4]; \
      const unsigned int mu = MQ[hp2]; \
      _Pragma("unroll") \
      for (int jj = 0; jj < 4; ++jj) { \
        const unsigned int c = BUF[jj][hp2]; \
        dot2acc(c, mu, kvacc[jj]); \
        _Pragma("unroll") \
        for (int ii = 0; ii < 4; ++ii) pkmaxdot(ra0[ii], c, mu, acc[ii][jj]); \
        _Pragma("unroll") \
        for (int ii = 0; ii < 4; ++ii) pkmaxdot(ra1[ii], c, mu, acc2[ii][jj]); \
      } \
    } \
  } while (0)

  {
    uint4v A[4], B[4], C[4];
    uint4v MA, MB, MC;
    LOADC(A, MA, 0); LOADC(B, MB, 1); LOADC(C, MC, 2);
    COMPG(A, MA, 0); LOADC(A, MA, 3);
    COMPG(B, MB, 1); LOADC(B, MB, 4);
    COMPG(C, MC, 2); LOADC(C, MC, 5);
    COMPG(A, MA, 3); LOADC(A, MA, 6);
    COMPG(B, MB, 4); LOADC(B, MB, 7);
    COMPG(C, MC, 5);
    COMPG(A, MA, 6);
    COMPG(B, MB, 7);
  }
#undef LOADC
#undef COMPG

  #pragma unroll
  for (int ii = 0; ii < 4; ++ii)
    #pragma unroll
    for (int jj = 0; jj < 4; ++jj) {
      part[w][li * 8 + ii][lj + 16 * jj]     = acc[ii][jj];
      part[w][li * 8 + 4 + ii][lj + 16 * jj] = acc2[ii][jj];
    }
  if (li == 0) {
    #pragma unroll
    for (int jj = 0; jj < 4; ++jj) partkv[w][lj + 16 * jj] = kvacc[jj];
  }
  __syncthreads();

  // combine + sigmoid: 256 threads x 8 outputs
  const int jl = t & 63, ib = (t >> 6) * 8;
  const float kvt = partkv[0][jl] + partkv[1][jl] + partkv[2][jl] + partkv[3][jl];
  const float base = b2v[0] - kvt;           // Kv[j] = b2 - sum_h s*Cn
  #pragma unroll
  for (int u = 0; u < 8; ++u) {
    const int il = ib + u;
    const float x = part[0][il][jl] + part[1][il][jl] +
                    part[2][il][jl] + part[3][il][jl] + base;
    out[(i0 + il) * NN + j0 + jl] = 1.f / (1.f + __expf(-x));
  }
}

extern "C" void kernel_launch(void* const* d_in, const int* in_sizes, int n_in,
                              void* d_out, int out_size, void* d_ws, size_t ws_size,
                              hipStream_t stream) {
  const float* z  = (const float*)d_in[0];
  const float* W1 = (const float*)d_in[1];
  const float* b1 = (const float*)d_in[2];
  const float* W2 = (const float*)d_in[3];
  const float* b2 = (const float*)d_in[4];
  float* out = (float*)d_out;
  char* ws = (char*)d_ws;

  k1_fused<<<dim3(64, 8), 256, 0, stream>>>(z, W1, b1, W2, ws);
  k2_pair<<<dim3(32, 16), 256, 0, stream>>>(
      (const unsigned int*)(ws + R2_OFF), (const unsigned int*)(ws + CT_OFF),
      W2, b2, out);
}